// Round 5
// baseline (754.913 us; speedup 1.0000x reference)
//
#include <hip/hip_runtime.h>
#include <math.h>

// StackedLSTM: B=2048, T=2048, D=H=6, 2 layers, softmax(h_last) -> [2048, 6] fp32.
//
// R4 layout: ONE batch per wave; lane = (layer, unit, gate).
//   l = lane>>5 (layer), u = (lane>>2)&7 (unit; 6,7 dummy), g = lane&3
//   (gate: 0=i, 1=f, 2=g, 3=o).  Quad (4 lanes) = one (layer,unit):
//   all four gate activations live in one quad -> cell update is quad-local
//   via 4 quad_perm DPP broadcasts.  Layer 1 runs one step behind layer 0.
//
// Why (from R2/R3 counters): wall = max(chain latency, per-SIMD issue).
//   R2 (bpermute h): chain-bound, ~200+ cyc of LDS-pipe latency/step.
//   R3 (readlane, pair layout): issue-bound, 82% VALUBusy, ~160 inst/step/wave.
// R4 minimizes BOTH: one row per lane (18 FMA, 1 exp+1 rcp per lane-step),
//   h via readlane->SGPR (VALU pipe), x via 4-deep VGPR prefetch ring from
//   global (LDS fully eliminated: no barriers, no ds_read, no copies; loop
//   unrolled x4 so ring slots are static registers).
//
// R5 fix vs R4: cell tanh had a sign bug —
//   e2 = exp2(-2·log2e·cn) with th = 1 - 2/(1+e2) gives -tanh(cn).
//   Correct reconstruction for the negated exponent: th = 2/(1+e2) - 1.

#define TSTEPS 2048
#define LOG2E 1.442695040889f

__device__ __forceinline__ float fast_rcp(float v) { return __builtin_amdgcn_rcpf(v); }

#if __has_builtin(__builtin_amdgcn_exp2f)
#define EXP2F(x) __builtin_amdgcn_exp2f(x)
#else
#define EXP2F(x) __expf((x) * 0.69314718056f)
#endif

__device__ __forceinline__ float rdlane_f(float v, int srclane) {
    return __int_as_float(__builtin_amdgcn_readlane(__float_as_int(v), srclane));
}

// quad_perm broadcast of quad-lane L to all 4 lanes of the quad
#define QPERM(v, CTRL) \
    __int_as_float(__builtin_amdgcn_mov_dpp(__float_as_int(v), (CTRL), 0xF, 0xF, true))

__global__ __launch_bounds__(64, 1)
void stacked_lstm_kernel(const float* __restrict__ x,
                         const float* __restrict__ Wih0, const float* __restrict__ Whh0,
                         const float* __restrict__ bih0, const float* __restrict__ bhh0,
                         const float* __restrict__ Wih1, const float* __restrict__ Whh1,
                         const float* __restrict__ bih1, const float* __restrict__ bhh1,
                         float* __restrict__ out)
{
    const int lane = threadIdx.x;
    const int l = lane >> 5;            // layer
    const int u = (lane >> 2) & 7;      // unit (6,7 dummy)
    const int g = lane & 3;             // gate: 0=i 1=f 2=g 3=o
    const int uc = (u < 6) ? u : 5;
    const int r = g * 6 + uc;           // PyTorch row: i=0..5 f=6..11 g=12..17 o=18..23
    const long b = (long)blockIdx.x;

    // act(v): i,f,o -> sigmoid = rcp(1+exp2(-LOG2E*v))
    //         g     -> tanh    = 2*rcp(1+exp2(-2*LOG2E*v)) - 1
    const float sc = (g == 2) ? (-2.0f * LOG2E) : (-LOG2E);
    const float cA = (g == 2) ? 2.0f : 1.0f;
    const float dA = (g == 2) ? -1.0f : 0.0f;

    // Zero-padded 3-term weights (scale folded in):
    //   L0: gate = dot(x, wx) + dot(h0, wh0)           (wh1 = 0)
    //   L1: gate = dot(h0, wh0) + dot(h1, wh1)         (wx  = 0)
    float wx[6], wh0[6], wh1[6];
#pragma unroll
    for (int k = 0; k < 6; ++k) {
        const float a0 = Wih0[r * 6 + k] * sc, b0 = Whh0[r * 6 + k] * sc;
        const float a1 = Wih1[r * 6 + k] * sc, b1 = Whh1[r * 6 + k] * sc;
        wx[k]  = l ? 0.0f : a0;
        wh0[k] = l ? a1   : b0;
        wh1[k] = l ? b1   : 0.0f;
    }
    const float bS = l ? (bih1[r] + bhh1[r]) * sc : (bih0[r] + bhh0[r]) * sc;

    const float* xb = x + b * (TSTEPS * 6);

    // x prefetch ring: 4 steps x 6 floats in VGPRs (wave-uniform broadcast loads;
    // 24B rows -> float2 granularity for alignment)
    float2 xs0[3], xs1[3], xs2[3], xs3[3];
    {
        const float2* xp = (const float2*)xb;
        xs0[0] = xp[0]; xs0[1] = xp[1]; xs0[2] = xp[2];
        xs1[0] = xp[3]; xs1[1] = xp[4]; xs1[2] = xp[5];
        xs2[0] = xp[6]; xs2[1] = xp[7]; xs2[2] = xp[8];
        xs3[0] = xp[9]; xs3[1] = xp[10]; xs3[2] = xp[11];
    }

    float hv = 0.0f;   // own (layer,unit) h, replicated across the quad
    float c  = 0.0f;   // own cell state, replicated across the quad

// One timestep. XS = static ring slot (t&3); tp = row to prefetch into it.
#define STEP(XS, tp)                                                          \
    {                                                                         \
        float h0v[6], h1v[6];                                                 \
        _Pragma("unroll")                                                     \
        for (int k = 0; k < 6; ++k) {                                         \
            h0v[k] = rdlane_f(hv, 4 * k);        /* layer-0 unit k */         \
            h1v[k] = rdlane_f(hv, 32 + 4 * k);   /* layer-1 unit k */         \
        }                                                                     \
        const float xv[6] = {XS[0].x, XS[0].y, XS[1].x,                       \
                             XS[1].y, XS[2].x, XS[2].y};                      \
        float sx = 0.0f, s0 = bS, s1 = 0.0f;                                  \
        _Pragma("unroll")                                                     \
        for (int k = 0; k < 6; ++k) {                                         \
            sx = fmaf(xv[k],  wx[k],  sx);                                    \
            s0 = fmaf(h0v[k], wh0[k], s0);                                    \
            s1 = fmaf(h1v[k], wh1[k], s1);                                    \
        }                                                                     \
        {   /* refill this slot with x[tp] (WAR: after consumption) */        \
            const float2* xq = (const float2*)(xb + (size_t)(tp) * 6);        \
            XS[0] = xq[0]; XS[1] = xq[1]; XS[2] = xq[2];                      \
        }                                                                     \
        const float s  = (sx + s0) + s1;                                      \
        const float e  = EXP2F(s);                                            \
        const float rc = fast_rcp(1.0f + e);                                  \
        const float a  = fmaf(cA, rc, dA);   /* i/f/o: sigmoid, g: tanh */    \
        const float bi = QPERM(a, 0x00);                                      \
        const float bf = QPERM(a, 0x55);                                      \
        const float bg = QPERM(a, 0xAA);                                      \
        const float bo = QPERM(a, 0xFF);                                      \
        const float cn = fmaf(bf, c, bi * bg);                                \
        const float e2 = EXP2F(cn * (-2.0f * LOG2E));                         \
        const float th = fmaf(2.0f, fast_rcp(1.0f + e2), -1.0f); /* tanh */   \
        hv = bo * th;                                                         \
        c  = cn;                                                              \
    }

    // t = 0: layer 0 computes step 0; layer 1 computes a phantom -> squash.
    STEP(xs0, 4)
    if (l) { hv = 0.0f; c = 0.0f; }

    // main: t = 1..2048 (at iter t: L0 does step t, L1 does step t-1).
    // 2048 iters = 512 x 4; slots cycle 1,2,3,0.  Prefetch t+4, clamped to
    // row 2047 (tail re-reads; consumed only by phantom L0 steps).
    for (int tb = 1; tb <= TSTEPS - 3; tb += 4) {
        const int p0 = (tb + 4 < TSTEPS) ? tb + 4 : TSTEPS - 1;
        const int p1 = (tb + 5 < TSTEPS) ? tb + 5 : TSTEPS - 1;
        const int p2 = (tb + 6 < TSTEPS) ? tb + 6 : TSTEPS - 1;
        const int p3 = (tb + 7 < TSTEPS) ? tb + 7 : TSTEPS - 1;
        STEP(xs1, p0)
        STEP(xs2, p1)
        STEP(xs3, p2)
        STEP(xs0, p3)
    }

    // ---- epilogue: h1(T-1) lives on layer-1 quads (lanes 32+4k) ----
    const float v0 = rdlane_f(hv, 32), v1 = rdlane_f(hv, 36), v2 = rdlane_f(hv, 40);
    const float v3 = rdlane_f(hv, 44), v4 = rdlane_f(hv, 48), v5 = rdlane_f(hv, 52);
    const float mx = fmaxf(fmaxf(fmaxf(v0, v1), fmaxf(v2, v3)), fmaxf(v4, v5));
    const float e0 = __expf(v0 - mx), e1 = __expf(v1 - mx), e2s = __expf(v2 - mx);
    const float e3 = __expf(v3 - mx), e4 = __expf(v4 - mx), e5 = __expf(v5 - mx);
    const float sum = ((e0 + e1) + (e2s + e3)) + (e4 + e5);
    const float rs = fast_rcp(sum);
    if (lane < 6) {
        const float mine = (lane == 0) ? e0 : (lane == 1) ? e1 : (lane == 2) ? e2s
                         : (lane == 3) ? e3 : (lane == 4) ? e4 : e5;
        out[b * 6 + lane] = mine * rs;
    }
}

extern "C" void kernel_launch(void* const* d_in, const int* in_sizes, int n_in,
                              void* d_out, int out_size, void* d_ws, size_t ws_size,
                              hipStream_t stream) {
    (void)in_sizes; (void)n_in; (void)d_ws; (void)ws_size; (void)out_size;
    const float* x    = (const float*)d_in[0];
    const float* Wih0 = (const float*)d_in[1];
    const float* Whh0 = (const float*)d_in[2];
    const float* bih0 = (const float*)d_in[3];
    const float* bhh0 = (const float*)d_in[4];
    const float* Wih1 = (const float*)d_in[5];
    const float* Whh1 = (const float*)d_in[6];
    const float* bih1 = (const float*)d_in[7];
    const float* bhh1 = (const float*)d_in[8];
    float* outp = (float*)d_out;

    // 1 batch per wave: 2048 blocks x 64 threads = 2 waves/SIMD machine-wide.
    stacked_lstm_kernel<<<2048, 64, 0, stream>>>(
        x, Wih0, Whh0, bih0, bhh0, Wih1, Whh1, bih1, bhh1, outp);
}

// Round 6
// 652.730 us; speedup vs baseline: 1.1565x; 1.1565x over previous
//
#include <hip/hip_runtime.h>
#include <math.h>

// StackedLSTM: B=2048, T=2048, D=H=6, 2 layers, softmax(h_last) -> [2048, 6] fp32.
//
// R6: each 16-lane DPP row = a self-contained 2-layer LSTM for ONE batch.
//   Within a row: lane = 2j+p (unit j=0..5, pair p; lanes 12-15 pad).
//   Each lane runs BOTH layers' (A,B) gate rows: A = i(p=0)/g(p=1), B = f/o.
//   Layer 1 runs one timestep behind layer 0 (pipelined, same instr stream).
//   Wave = 4 rows: rows 0,1 = batches 2b,2b+1; rows 2,3 mirror (writes masked).
//
// All cross-lane traffic is intra-row DPP (VALU pipe):
//   - h gather: quad_perm bcast (0x00 / 0xAA) + row_ror:4/8/12 -> 8 slots
//     (pad quad's 2 slots zero-weighted).  Rotation DIRECTION is probed at
//     init by pushing each lane's unit id through the identical tree; weights
//     are loaded in arrival order, so HW ror semantics can't break us.
//   - (i,f)<->(g,o) pair exchange: quad_perm(1,0,3,2) = 0xB1.
// Evidence: R3/R5 (readlane) pinned at ~770 cyc/step chain regardless of
// issue; R2 (bpermute) 535 cyc per step x 2 batches, LDS-latency bound.
// R6 removes LDS/readlane from the chain entirely; 1024 waves = 1/SIMD.

#define TSTEPS 2048
#define LOG2E 1.442695040889f

__device__ __forceinline__ float fast_rcp(float v) { return __builtin_amdgcn_rcpf(v); }

#if __has_builtin(__builtin_amdgcn_exp2f)
#define EXP2F(x) __builtin_amdgcn_exp2f(x)
#else
#define EXP2F(x) __expf((x) * 0.69314718056f)
#endif

#define DPPI(v, CTRL) __builtin_amdgcn_mov_dpp((v), (CTRL), 0xF, 0xF, true)
#define DPPF(v, CTRL) __int_as_float(DPPI(__float_as_int(v), (CTRL)))

// 8-slot intra-row gather: quad-even, quad-odd, then row_ror 4/8/12 of each.
#define GATHER8(dst, src)                                                   \
    {                                                                       \
        const float _dA = DPPF((src), 0x00);   /* bcast quad lane 0 */      \
        const float _dB = DPPF((src), 0xAA);   /* bcast quad lane 2 */      \
        dst[0] = _dA;               dst[1] = _dB;                           \
        dst[2] = DPPF(_dA, 0x124);  dst[3] = DPPF(_dB, 0x124);              \
        dst[4] = DPPF(_dA, 0x128);  dst[5] = DPPF(_dB, 0x128);              \
        dst[6] = DPPF(_dA, 0x12C);  dst[7] = DPPF(_dB, 0x12C);              \
    }

__global__ __launch_bounds__(64, 1)
void stacked_lstm_kernel(const float* __restrict__ x,
                         const float* __restrict__ Wih0, const float* __restrict__ Whh0,
                         const float* __restrict__ bih0, const float* __restrict__ bhh0,
                         const float* __restrict__ Wih1, const float* __restrict__ Whh1,
                         const float* __restrict__ bih1, const float* __restrict__ bhh1,
                         float* __restrict__ out)
{
    const int lane = threadIdx.x;
    const int rl  = lane & 15;            // lane within 16-lane row
    const int row = (lane >> 4) & 1;      // rows 2,3 mirror rows 0,1
    const int j  = rl >> 1;               // unit 0..7 (6,7 pad)
    const int p  = rl & 1;                // 0 -> (i,f) rows; 1 -> (g,o) rows
    const int uc = (j < 6) ? j : 5;
    const long b = (long)blockIdx.x * 2 + row;

    // ---- probe the gather tree with unit ids (immune to ror semantics) ----
    int ids[8];
    {
        const int idv = (rl < 12) ? j : 6;   // pad quad marked >=6
        const int dA = DPPI(idv, 0x00);
        const int dB = DPPI(idv, 0xAA);
        ids[0] = dA;               ids[1] = dB;
        ids[2] = DPPI(dA, 0x124);  ids[3] = DPPI(dB, 0x124);
        ids[4] = DPPI(dA, 0x128);  ids[5] = DPPI(dB, 0x128);
        ids[6] = DPPI(dA, 0x12C);  ids[7] = DPPI(dB, 0x12C);
    }

    // ---- per-lane weights, exp2-domain scale folded in, arrival-ordered ----
    // PyTorch gate rows: i=0..5, f=6..11, g=12..17, o=18..23
    const int rA = p * 12 + uc;           // p=0: i-row ; p=1: g-row
    const int rB = rA + 6;                // p=0: f-row ; p=1: o-row
    // sigmoid(v)=rcp(1+exp2(-L v)); tanh(v)=2*rcp(1+exp2(-2L v))-1
    const float scA = p ? (-2.0f * LOG2E) : (-LOG2E);
    const float scB = -LOG2E;
    const float cAc = p ? 2.0f : 1.0f;
    const float dAc = p ? -1.0f : 0.0f;

    float wxA[6], wxB[6];                       // L0 x-term (natural order)
#pragma unroll
    for (int k = 0; k < 6; ++k) {
        wxA[k] = Wih0[rA * 6 + k] * scA;
        wxB[k] = Wih0[rB * 6 + k] * scB;
    }
    float whA0[8], whB0[8], wiA1[8], wiB1[8], whA1[8], whB1[8];  // gather order
#pragma unroll
    for (int s = 0; s < 8; ++s) {
        const int id = ids[s];
        const bool ok = (id >= 0) && (id < 6);
        whA0[s] = ok ? Whh0[rA * 6 + id] * scA : 0.0f;
        whB0[s] = ok ? Whh0[rB * 6 + id] * scB : 0.0f;
        wiA1[s] = ok ? Wih1[rA * 6 + id] * scA : 0.0f;
        wiB1[s] = ok ? Wih1[rB * 6 + id] * scB : 0.0f;
        whA1[s] = ok ? Whh1[rA * 6 + id] * scA : 0.0f;
        whB1[s] = ok ? Whh1[rB * 6 + id] * scB : 0.0f;
    }
    const float bA0 = (bih0[rA] + bhh0[rA]) * scA;
    const float bB0 = (bih0[rB] + bhh0[rB]) * scB;
    const float bA1 = (bih1[rA] + bhh1[rA]) * scA;
    const float bB1 = (bih1[rB] + bhh1[rB]) * scB;

    // ---- x prefetch ring: 4 steps x 3 float2 in VGPRs ----
    const float* xb = x + b * (TSTEPS * 6);
    float2 xs0[3], xs1[3], xs2[3], xs3[3];
    {
        const float2* xp = (const float2*)xb;
        xs0[0] = xp[0];  xs0[1] = xp[1];  xs0[2] = xp[2];
        xs1[0] = xp[3];  xs1[1] = xp[4];  xs1[2] = xp[5];
        xs2[0] = xp[6];  xs2[1] = xp[7];  xs2[2] = xp[8];
        xs3[0] = xp[9];  xs3[1] = xp[10]; xs3[2] = xp[11];
    }

    float hv0 = 0.0f, c0 = 0.0f;   // layer-0 state of own unit (pair-duplicated)
    float hv1 = 0.0f, c1 = 0.0f;   // layer-1 state

#define STEP(XS, tp)                                                        \
    {                                                                       \
        float g0[8], g1[8];                                                 \
        GATHER8(g0, hv0)                                                    \
        GATHER8(g1, hv1)                                                    \
        const float xv[6] = {XS[0].x, XS[0].y, XS[1].x,                     \
                             XS[1].y, XS[2].x, XS[2].y};                    \
        float sA0 = bA0, sB0 = bB0, sA1 = bA1, sB1 = bB1;                   \
        float pA0 = 0.0f, pB0 = 0.0f, qA1 = 0.0f, qB1 = 0.0f;               \
        _Pragma("unroll")                                                   \
        for (int k = 0; k < 6; ++k) {                                       \
            sA0 = fmaf(xv[k], wxA[k], sA0);                                 \
            sB0 = fmaf(xv[k], wxB[k], sB0);                                 \
        }                                                                   \
        _Pragma("unroll")                                                   \
        for (int s = 0; s < 8; ++s) {                                       \
            pA0 = fmaf(g0[s], whA0[s], pA0);                                \
            pB0 = fmaf(g0[s], whB0[s], pB0);                                \
            sA1 = fmaf(g0[s], wiA1[s], sA1);                                \
            sB1 = fmaf(g0[s], wiB1[s], sB1);                                \
            qA1 = fmaf(g1[s], whA1[s], qA1);                                \
            qB1 = fmaf(g1[s], whB1[s], qB1);                                \
        }                                                                   \
        {   /* refill this ring slot with x[tp] (after consumption) */      \
            const float2* xq = (const float2*)(xb + (size_t)(tp) * 6);      \
            XS[0] = xq[0]; XS[1] = xq[1]; XS[2] = xq[2];                    \
        }                                                                   \
        sA0 += pA0; sB0 += pB0; sA1 += qA1; sB1 += qB1;                     \
        /* layer 0 */                                                       \
        const float eA0 = EXP2F(sA0), eB0 = EXP2F(sB0);                     \
        const float aA0 = fmaf(cAc, fast_rcp(1.0f + eA0), dAc);             \
        const float aB0 = fast_rcp(1.0f + eB0);                             \
        const float xA0 = DPPF(aA0, 0xB1), xB0 = DPPF(aB0, 0xB1);           \
        const float ig0 = aA0 * xA0;                                        \
        const float gf0 = p ? xB0 : aB0;                                    \
        const float go0 = p ? aB0 : xB0;                                    \
        const float cn0 = fmaf(gf0, c0, ig0);                               \
        const float t0e = EXP2F(cn0 * (-2.0f * LOG2E));                     \
        const float th0 = fmaf(2.0f, fast_rcp(1.0f + t0e), -1.0f);          \
        hv0 = go0 * th0; c0 = cn0;                                          \
        /* layer 1 (one step behind) */                                     \
        const float eA1 = EXP2F(sA1), eB1 = EXP2F(sB1);                     \
        const float aA1 = fmaf(cAc, fast_rcp(1.0f + eA1), dAc);             \
        const float aB1 = fast_rcp(1.0f + eB1);                             \
        const float xA1 = DPPF(aA1, 0xB1), xB1 = DPPF(aB1, 0xB1);           \
        const float ig1 = aA1 * xA1;                                        \
        const float gf1 = p ? xB1 : aB1;                                    \
        const float go1 = p ? aB1 : xB1;                                    \
        const float cn1 = fmaf(gf1, c1, ig1);                               \
        const float t1e = EXP2F(cn1 * (-2.0f * LOG2E));                     \
        const float th1 = fmaf(2.0f, fast_rcp(1.0f + t1e), -1.0f);          \
        hv1 = go1 * th1; c1 = cn1;                                          \
    }

    // t = 0: layer 0 does step 0; layer 1 computes a phantom -> squash.
    STEP(xs0, 4)
    hv1 = 0.0f; c1 = 0.0f;

    // t = 1..2048 (at iter t: L0 does step t, L1 does step t-1).
    // Prefetch row t+4, clamped to 2047 (tail re-reads feed phantom L0 steps).
    for (int tb = 1; tb <= TSTEPS - 3; tb += 4) {
        const int p0 = (tb + 4 < TSTEPS) ? tb + 4 : TSTEPS - 1;
        const int p1 = (tb + 5 < TSTEPS) ? tb + 5 : TSTEPS - 1;
        const int p2 = (tb + 6 < TSTEPS) ? tb + 6 : TSTEPS - 1;
        const int p3 = (tb + 7 < TSTEPS) ? tb + 7 : TSTEPS - 1;
        STEP(xs1, p0)
        STEP(xs2, p1)
        STEP(xs3, p2)
        STEP(xs0, p3)
    }

    // ---- epilogue: hv1 = h1(T-1); per-lane softmax via one more gather ----
    float gf[8];
    GATHER8(gf, hv1)
    float mx = -3.0e38f;
#pragma unroll
    for (int s = 0; s < 8; ++s) {
        const float v = (ids[s] < 6) ? gf[s] : -3.0e38f;
        mx = fmaxf(mx, v);
    }
    float sum = 0.0f;
#pragma unroll
    for (int s = 0; s < 8; ++s) {
        const float e = (ids[s] < 6) ? __expf(gf[s] - mx) : 0.0f;
        sum += e;
    }
    const float rs = fast_rcp(sum);
    if (p == 0 && j < 6 && lane < 32) {
        out[b * 6 + j] = __expf(hv1 - mx) * rs;
    }
}

extern "C" void kernel_launch(void* const* d_in, const int* in_sizes, int n_in,
                              void* d_out, int out_size, void* d_ws, size_t ws_size,
                              hipStream_t stream) {
    (void)in_sizes; (void)n_in; (void)d_ws; (void)ws_size; (void)out_size;
    const float* x    = (const float*)d_in[0];
    const float* Wih0 = (const float*)d_in[1];
    const float* Whh0 = (const float*)d_in[2];
    const float* bih0 = (const float*)d_in[3];
    const float* bhh0 = (const float*)d_in[4];
    const float* Wih1 = (const float*)d_in[5];
    const float* Whh1 = (const float*)d_in[6];
    const float* bih1 = (const float*)d_in[7];
    const float* bhh1 = (const float*)d_in[8];
    float* outp = (float*)d_out;

    // 2 batches per wave (rows 0,1; rows 2,3 mirror): 1024 blocks x 64 threads
    // = 1024 waves = 1 wave per SIMD machine-wide.
    stacked_lstm_kernel<<<1024, 64, 0, stream>>>(
        x, Wih0, Whh0, bih0, bhh0, Wih1, Whh1, bih1, bhh1, outp);
}